// Round 1
// 1017.523 us; speedup vs baseline: 1.6088x; 1.6088x over previous
//
#include <hip/hip_runtime.h>

#define D 128

typedef __attribute__((ext_vector_type(8))) short bf16x8;
typedef __attribute__((ext_vector_type(4))) float f32x4;

// ---------------- bf16 split helpers ----------------

__device__ __forceinline__ ushort f2bf_rn(float x) {
    uint u = __float_as_uint(x);
    u += 0x7fff + ((u >> 16) & 1);          // round-to-nearest-even
    return (ushort)(u >> 16);
}
__device__ __forceinline__ float bf2f(ushort h) {
    return __uint_as_float(((uint)h) << 16);
}
// pack two floats into one uint of hi-bf16 and one uint of lo-bf16
__device__ __forceinline__ void split2(float a, float b, uint& h, uint& lo) {
    ushort ha = f2bf_rn(a), hb = f2bf_rn(b);
    float  ra = a - bf2f(ha), rb = b - bf2f(hb);
    ushort la = f2bf_rn(ra), lb = f2bf_rn(rb);
    h  = (uint)ha | ((uint)hb << 16);
    lo = (uint)la | ((uint)lb << 16);
}

// ---------------- preprocessing ----------------

__global__ void hist_kernel(const int* __restrict__ assign, int n, int* __restrict__ cnt) {
    int i = blockIdx.x * blockDim.x + threadIdx.x;
    if (i < n) atomicAdd(&cnt[assign[i]], 1);
}

__global__ void scan_kernel(const int* __restrict__ cnt, int n, int* __restrict__ head) {
    __shared__ int part[1024];
    const int t = threadIdx.x;
    const int per = (n + 1023) >> 10;
    const int lo = t * per;
    const int hi = min(lo + per, n);
    int s = 0;
    for (int i = lo; i < hi; ++i) s += cnt[i];
    part[t] = s;
    __syncthreads();
    for (int d = 1; d < 1024; d <<= 1) {
        int v = (t >= d) ? part[t - d] : 0;
        __syncthreads();
        part[t] += v;
        __syncthreads();
    }
    int base = (t > 0) ? part[t - 1] : 0;
    for (int i = lo; i < hi; ++i) { head[i] = base; base += cnt[i]; }
}

__global__ void perm_kernel(const int* __restrict__ assign, int n,
                            int* __restrict__ head, int* __restrict__ perm) {
    int i = blockIdx.x * blockDim.x + threadIdx.x;
    if (i < n) {
        int p = atomicAdd(&head[assign[i]], 1);
        perm[p] = i;
    }
}

// W is [out][in] row-major == exactly the [col][k] layout the B-frag wants.
// Elementwise split into hi/lo bf16 (no transpose needed).
__global__ void split_w(const float* __restrict__ W,
                        ushort* __restrict__ Whi, ushort* __restrict__ Wlo) {
    int i = blockIdx.x * 256 + threadIdx.x;   // 0..16383
    float x = W[i];
    ushort h = f2bf_rn(x);
    Whi[i] = h;
    Wlo[i] = f2bf_rn(x - bf2f(h));
}

// ---------------- unified 128x128 MFMA GEMM ----------------
// Block: 256 threads = 4 waves. Tile: 128 rows (perm-ordered if PERM) x 128 cols.
// Wave w owns rows [32w,32w+32): 2 row-tiles x 8 col-tiles of 16x16x32 bf16 MFMA.
// fp32 emulated as hi/lo bf16 split, 3 MFMAs per tile per k-chunk (error ~2^-17 rel).
// LDS staging stride 40 bf16 (80 B) -> banks balanced, rows stay 16B-aligned.
// SCATTER epilogue: block-level segment reduction in LDS; rows are segment-sorted,
// so interior segments get plain stores (sole writer); only the <=2 boundary
// segments per block use atomics (kills the 700 MB atomic write amplification).
template<bool PERM, bool SCATTER, bool RELU, bool SCALE>
__global__ __launch_bounds__(256, 3)
void gemm128_mfma(const float* __restrict__ X,
                  const ushort* __restrict__ Whi,
                  const ushort* __restrict__ Wlo,
                  const float*  __restrict__ bias,
                  const int*    __restrict__ perm,
                  const int*    __restrict__ assign,
                  const int*    __restrict__ cnt_in,
                  float* __restrict__ Out,
                  int nrows)
{
    __shared__ __align__(16) ushort sm[4 * 128 * 40];   // 40960 B staging
    ushort* XsH = sm;                                   // [128 rows][40] bf16 hi
    ushort* XsL = sm + 128 * 40;                        // lo
    ushort* WsH = sm + 2 * 128 * 40;                    // [128 cols][40] bf16 hi
    ushort* WsL = sm + 3 * 128 * 40;                    // lo
    float*  Acc = (float*)sm;                           // [128][65] fp32 (aliases staging)
    __shared__ int rowmap[128];
    __shared__ int segs[128];
    __shared__ int srow[129];
    __shared__ int segid[128];
    __shared__ unsigned long long bmask[2];

    const int t  = threadIdx.x;
    const int l  = t & 63;
    const int w  = t >> 6;
    const int p0 = blockIdx.x * 128;
    const int nvalid = min(128, nrows - p0);

    if (t < 128) {
        int p  = p0 + t;
        int pc = (p < nrows) ? p : (nrows - 1);
        int row = PERM ? perm[pc] : pc;
        rowmap[t] = row;
        if (SCATTER) segs[t] = assign[row];
    }
    __syncthreads();

    // staging identity: thread covers 16 k of one row (X) and one col (W)
    const int sr = t >> 1;
    const int sk = (t & 1) * 16;
    const float*  xrow = X   + (size_t)rowmap[sr] * D + sk;
    const ushort* whr  = Whi + sr * D + sk;
    const ushort* wlr  = Wlo + sr * D + sk;

    // fragment identity
    const int fr = l & 15;          // A row / B col / C col within 16-tile
    const int fk = (l >> 4) * 8;    // k-group (8 contiguous bf16)
    const int rb = w * 32;          // wave's row base

    float bb[8];
    #pragma unroll
    for (int ct = 0; ct < 8; ++ct) bb[ct] = bias[ct * 16 + fr];

    f32x4 acc[2][8];
    #pragma unroll
    for (int rt = 0; rt < 2; ++rt)
        #pragma unroll
        for (int ct = 0; ct < 8; ++ct)
            acc[rt][ct] = (f32x4){0.f, 0.f, 0.f, 0.f};

    // prefetch chunk 0 of X
    float4 xv0 = *(const float4*)(xrow + 0);
    float4 xv1 = *(const float4*)(xrow + 4);
    float4 xv2 = *(const float4*)(xrow + 8);
    float4 xv3 = *(const float4*)(xrow + 12);

    for (int kc = 0; kc < D; kc += 32) {
        // W loads (L2-hot, issued pre-barrier; only touch global)
        uint4 wh0 = *(const uint4*)(whr + kc);
        uint4 wh1 = *(const uint4*)(whr + kc + 8);
        uint4 wl0 = *(const uint4*)(wlr + kc);
        uint4 wl1 = *(const uint4*)(wlr + kc + 8);

        __syncthreads();   // previous chunk's MFMA frag reads complete

        uint4 H0, L0, H1, L1;
        split2(xv0.x, xv0.y, H0.x, L0.x);
        split2(xv0.z, xv0.w, H0.y, L0.y);
        split2(xv1.x, xv1.y, H0.z, L0.z);
        split2(xv1.z, xv1.w, H0.w, L0.w);
        split2(xv2.x, xv2.y, H1.x, L1.x);
        split2(xv2.z, xv2.w, H1.y, L1.y);
        split2(xv3.x, xv3.y, H1.z, L1.z);
        split2(xv3.z, xv3.w, H1.w, L1.w);
        *(uint4*)(XsH + sr * 40 + sk)     = H0;
        *(uint4*)(XsH + sr * 40 + sk + 8) = H1;
        *(uint4*)(XsL + sr * 40 + sk)     = L0;
        *(uint4*)(XsL + sr * 40 + sk + 8) = L1;
        *(uint4*)(WsH + sr * 40 + sk)     = wh0;
        *(uint4*)(WsH + sr * 40 + sk + 8) = wh1;
        *(uint4*)(WsL + sr * 40 + sk)     = wl0;
        *(uint4*)(WsL + sr * 40 + sk + 8) = wl1;

        __syncthreads();

        // prefetch next X chunk; HBM latency hides under the MFMA cluster
        if (kc + 32 < D) {
            xv0 = *(const float4*)(xrow + kc + 32);
            xv1 = *(const float4*)(xrow + kc + 36);
            xv2 = *(const float4*)(xrow + kc + 40);
            xv3 = *(const float4*)(xrow + kc + 44);
        }

        bf16x8 aH0 = *(const bf16x8*)(XsH + (rb + fr) * 40 + fk);
        bf16x8 aL0 = *(const bf16x8*)(XsL + (rb + fr) * 40 + fk);
        bf16x8 aH1 = *(const bf16x8*)(XsH + (rb + 16 + fr) * 40 + fk);
        bf16x8 aL1 = *(const bf16x8*)(XsL + (rb + 16 + fr) * 40 + fk);
        #pragma unroll
        for (int ct = 0; ct < 8; ++ct) {
            bf16x8 bH = *(const bf16x8*)(WsH + (ct * 16 + fr) * 40 + fk);
            bf16x8 bL = *(const bf16x8*)(WsL + (ct * 16 + fr) * 40 + fk);
            acc[0][ct] = __builtin_amdgcn_mfma_f32_16x16x32_bf16(aH0, bL, acc[0][ct], 0, 0, 0);
            acc[0][ct] = __builtin_amdgcn_mfma_f32_16x16x32_bf16(aL0, bH, acc[0][ct], 0, 0, 0);
            acc[0][ct] = __builtin_amdgcn_mfma_f32_16x16x32_bf16(aH0, bH, acc[0][ct], 0, 0, 0);
            acc[1][ct] = __builtin_amdgcn_mfma_f32_16x16x32_bf16(aH1, bL, acc[1][ct], 0, 0, 0);
            acc[1][ct] = __builtin_amdgcn_mfma_f32_16x16x32_bf16(aL1, bH, acc[1][ct], 0, 0, 0);
            acc[1][ct] = __builtin_amdgcn_mfma_f32_16x16x32_bf16(aH1, bH, acc[1][ct], 0, 0, 0);
        }
    }

    const int r0 = rb + (l >> 4) * 4;   // C/D: row = (lane>>4)*4 + reg (within 16-tile)

    if (!SCATTER) {
        #pragma unroll
        for (int rt = 0; rt < 2; ++rt) {
            #pragma unroll
            for (int g = 0; g < 4; ++g) {
                const int row = p0 + r0 + rt * 16 + g;
                if (row < nrows) {
                    float s = 1.f;
                    bool nz = true;
                    if (SCALE) {
                        int c = cnt_in[row];
                        nz = (c > 0);
                        s  = nz ? 1.f / (float)c : 0.f;
                    }
                    #pragma unroll
                    for (int ct = 0; ct < 8; ++ct) {
                        float y = acc[rt][ct][g] * s + (nz ? bb[ct] : 0.f);
                        if (RELU) y = fmaxf(y, 0.f);
                        Out[(size_t)row * D + ct * 16 + fr] = y;
                    }
                }
            }
        }
        return;
    }

    // ---- scatter epilogue: block-level segment reduction ----
    // boundary analysis over the (segment-sorted) 128 rows
    if (t < 128) {
        bool isb = (t < nvalid) && (t == 0 || segs[t] != segs[t - 1]);
        unsigned long long m = __ballot(isb);
        if (l == 0) bmask[w] = m;
    }
    __syncthreads();
    const int nseg = __popcll(bmask[0]) + __popcll(bmask[1]);
    if (t < 128) {
        bool isb = (t < nvalid) && (t == 0 || segs[t] != segs[t - 1]);
        if (isb) {
            int lid = (t < 64)
                ? __popcll(bmask[0] & ((1ull << t) - 1))
                : __popcll(bmask[0]) + __popcll(bmask[1] & ((1ull << (t - 64)) - 1));
            srow[lid]  = t;
            segid[lid] = segs[t];
        }
    }
    if (t == 0) srow[nseg] = nvalid;

    // two column halves so Acc[128][65] fp32 fits in the staging LDS
    #pragma unroll
    for (int half = 0; half < 2; ++half) {
        __syncthreads();   // staging reads / previous flush done -> Acc writable
        #pragma unroll
        for (int rt = 0; rt < 2; ++rt) {
            #pragma unroll
            for (int g = 0; g < 4; ++g) {
                const int row = r0 + rt * 16 + g;
                #pragma unroll
                for (int c4 = 0; c4 < 4; ++c4) {
                    const int ct = half * 4 + c4;
                    float y = acc[rt][ct][g] + bb[ct];
                    if (RELU) y = fmaxf(y, 0.f);
                    Acc[row * 65 + c4 * 16 + fr] = y;
                }
            }
        }
        __syncthreads();
        for (int idx = t; idx < nseg * 64; idx += 256) {
            const int s = idx >> 6, c = idx & 63;
            const int rlo = srow[s], rhi = srow[s + 1];
            float sum = 0.f;
            for (int r = rlo; r < rhi; ++r) sum += Acc[r * 65 + c];
            float* o = Out + (size_t)segid[s] * D + half * 64 + c;
            if (s > 0 && s + 1 < nseg) *o = sum;      // interior: sole writer
            else unsafeAtomicAdd(o, sum);             // block-boundary segment
        }
    }
}

extern "C" void kernel_launch(void* const* d_in, const int* in_sizes, int n_in,
                              void* d_out, int out_size, void* d_ws, size_t ws_size,
                              hipStream_t stream) {
    const float* x_building = (const float*)d_in[0];   // 1048576 x 128
    const int*   assign_bc  = (const int*)  d_in[1];   // 1048576
    const int*   assign_ct  = (const int*)  d_in[2];   // 50000
    const float* w1 = (const float*)d_in[3];
    const float* b1 = (const float*)d_in[4];
    const float* w2 = (const float*)d_in[5];
    const float* b2 = (const float*)d_in[6];
    const float* w3 = (const float*)d_in[7];
    const float* b3 = (const float*)d_in[8];
    const float* w4 = (const float*)d_in[9];
    const float* b4 = (const float*)d_in[10];

    const int N_BUILD = 1048576;
    const int N_CABLE = 50000;
    const int N_TRANS = 2000;

    float* out = (float*)d_out;
    float* S_c = out;                        // 50000 x 128
    float* S_t = out + (size_t)N_CABLE * D;  // 2000 x 128

    // workspace layout: W splits first (keeps uint4 loads 16B-aligned)
    ushort* Wh1 = (ushort*)d_ws;
    ushort* Wl1 = Wh1 + D * D;
    ushort* Wh2 = Wl1 + D * D;
    ushort* Wl2 = Wh2 + D * D;
    ushort* Wh3 = Wl2 + D * D;
    ushort* Wl3 = Wh3 + D * D;
    ushort* Wh4 = Wl3 + D * D;
    ushort* Wl4 = Wh4 + D * D;
    int* cnt_c  = (int*)(Wl4 + D * D);       // 50000
    int* cnt_t  = cnt_c + N_CABLE;           // 2000
    int* head_c = cnt_t + N_TRANS;           // 50000
    int* head_t = head_c + N_CABLE;          // 2000
    int* perm_c = head_t + N_TRANS;          // 1048576
    int* perm_t = perm_c + N_BUILD;          // 50000

    hipMemsetAsync(d_out, 0, (size_t)out_size * sizeof(float), stream);
    hipMemsetAsync(cnt_c, 0, (size_t)(N_CABLE + N_TRANS) * sizeof(int), stream);

    // preprocessing: CSR perms + weight hi/lo splits
    hist_kernel<<<(N_BUILD + 255) / 256, 256, 0, stream>>>(assign_bc, N_BUILD, cnt_c);
    hist_kernel<<<(N_CABLE + 255) / 256, 256, 0, stream>>>(assign_ct, N_CABLE, cnt_t);
    scan_kernel<<<1, 1024, 0, stream>>>(cnt_c, N_CABLE, head_c);
    scan_kernel<<<1, 1024, 0, stream>>>(cnt_t, N_TRANS, head_t);
    perm_kernel<<<(N_BUILD + 255) / 256, 256, 0, stream>>>(assign_bc, N_BUILD, head_c, perm_c);
    perm_kernel<<<(N_CABLE + 255) / 256, 256, 0, stream>>>(assign_ct, N_CABLE, head_t, perm_t);
    split_w<<<64, 256, 0, stream>>>(w1, Wh1, Wl1);
    split_w<<<64, 256, 0, stream>>>(w2, Wh2, Wl2);
    split_w<<<64, 256, 0, stream>>>(w3, Wh3, Wl3);
    split_w<<<64, 256, 0, stream>>>(w4, Wh4, Wl4);

    // K1: scatter-sum relu(X@W1^T+b1) into S_c (perm order)
    gemm128_mfma<true, true, true, false><<<N_BUILD / 128, 256, 0, stream>>>(
        x_building, Wh1, Wl1, b1, perm_c, assign_bc, nullptr, S_c, N_BUILD);
    // K2: x_cable = (S_c/cnt)@W2^T + b2, in place
    gemm128_mfma<false, false, false, true><<<(N_CABLE + 127) / 128, 256, 0, stream>>>(
        S_c, Wh2, Wl2, b2, nullptr, nullptr, cnt_c, S_c, N_CABLE);
    // K3: scatter-sum relu(x_cable@W3^T+b3) into S_t (perm order)
    gemm128_mfma<true, true, true, false><<<(N_CABLE + 127) / 128, 256, 0, stream>>>(
        S_c, Wh3, Wl3, b3, perm_t, assign_ct, nullptr, S_t, N_CABLE);
    // K4: x_trans = (S_t/cnt)@W4^T + b4, in place
    gemm128_mfma<false, false, false, true><<<(N_TRANS + 127) / 128, 256, 0, stream>>>(
        S_t, Wh4, Wl4, b4, nullptr, nullptr, cnt_t, S_t, N_TRANS);
}